// Round 1
// baseline (281.839 us; speedup 1.0000x reference)
//
#include <hip/hip_runtime.h>
#include <math.h>

#define NN 50000
#define DD 128
#define HH 128
#define L1 64
#define L2 32
#define OO 10

typedef short v8s __attribute__((ext_vector_type(8)));   // 8 bf16 (4 VGPRs)
typedef float v4f __attribute__((ext_vector_type(4)));   // MFMA accumulator

// ---- bf16 helpers (manual: RNE pack) ----
__device__ __forceinline__ float bf2f_lo(unsigned u) { return __uint_as_float(u << 16); }
__device__ __forceinline__ float bf2f_hi(unsigned u) { return __uint_as_float(u & 0xffff0000u); }
__device__ __forceinline__ unsigned short f2bf(float f) {
    unsigned u = __float_as_uint(f);
    return (unsigned short)((u + 0x7fffu + ((u >> 16) & 1u)) >> 16);
}
__device__ __forceinline__ float gelu_f(float v) {
    return 0.5f * v * (1.f + erff(v * 0.70710678118654752f));
}

// ---------------- K0: transpose W, W1, W2 to bf16 B-operand layouts ----------
// wtb[128][136] = W^T; w1tb[64][136] = W1^T; w2tb[32][72] = W2^T (k-padded).
__global__ __launch_bounds__(256) void k_wprep(
    const float* __restrict__ W, const float* __restrict__ W1,
    const float* __restrict__ W2, unsigned short* __restrict__ wtb,
    unsigned short* __restrict__ w1tb, unsigned short* __restrict__ w2tb)
{
    int i = blockIdx.x * 256 + threadIdx.x;
    if (i < 128 * 136) {
        int n = i / 136, k = i % 136;
        wtb[i] = (k < DD) ? f2bf(W[k * HH + n]) : (unsigned short)0;
    } else if (i < 128 * 136 + 64 * 136) {
        int j = i - 128 * 136;
        int n = j / 136, k = j % 136;
        w1tb[j] = (k < HH) ? f2bf(W1[k * L1 + n]) : (unsigned short)0;
    } else if (i < 128 * 136 + 64 * 136 + 32 * 72) {
        int j = i - (128 * 136 + 64 * 136);
        int n = j / 72, k = j % 72;
        w2tb[j] = (k < L1) ? f2bf(W2[k * L2 + n]) : (unsigned short)0;
    }
}

// ---------------- K1: x -> interleaved bf16 + fused dst histogram -------------
// Pure streaming: xb[(n*2+b)*128 + c] = bf16(x[b][n][c]).  (A.(xW) == (A.x).W,
// so the dense GEMM moves to k_mlp where the A-tile is LDS-resident anyway.)
__global__ __launch_bounds__(256) void k_xcvt(
    const float* __restrict__ x, unsigned short* __restrict__ xb,
    const int* __restrict__ ei, int* __restrict__ counts, int E)
{
    const int gid = blockIdx.x * 256 + threadIdx.x;
    const int stride = gridDim.x * 256;
    const int HALF = NN * 32;                 // float4-chunks per batch
    for (int idx = gid; idx < 2 * HALF; idx += stride) {
        const int b = (idx >= HALF) ? 1 : 0;
        const int j = idx - b * HALF;
        const int n = j >> 5;
        const int c4 = j & 31;
        const float4 v = *(const float4*)(x + ((size_t)b * NN + n) * DD + c4 * 4);
        ushort4 o;
        o.x = f2bf(v.x); o.y = f2bf(v.y); o.z = f2bf(v.z); o.w = f2bf(v.w);
        *(ushort4*)(xb + ((size_t)n * 2 + b) * DD + c4 * 4) = o;
    }
    for (int e = gid; e < E; e += stride)
        atomicAdd(&counts[ei[(size_t)E + e]], 1);
}

// ---------------- multi-block scan, stage 1 ----------------
__global__ __launch_bounds__(1024) void k_scan1(
    const int* __restrict__ counts, int* __restrict__ offsets,
    int* __restrict__ blksum, int n)
{
    __shared__ int wsum[16], woff[16];
    const int tid = threadIdx.x, lane = tid & 63, wv = tid >> 6;
    const int i = blockIdx.x * 1024 + tid;
    int v = (i < n) ? counts[i] : 0;
    int x = v;
    #pragma unroll
    for (int d = 1; d < 64; d <<= 1) { int t = __shfl_up(x, d); if (lane >= d) x += t; }
    if (lane == 63) wsum[wv] = x;
    __syncthreads();
    if (wv == 0 && lane < 16) {
        int y = wsum[lane];
        #pragma unroll
        for (int d = 1; d < 16; d <<= 1) { int t = __shfl_up(y, d); if (lane >= d) y += t; }
        woff[lane] = y - wsum[lane];
        if (lane == 15) blksum[blockIdx.x] = y;
    }
    __syncthreads();
    if (i < n) offsets[i] = woff[wv] + (x - v);
}

// ---------------- multi-block scan, stage 2 ----------------
__global__ __launch_bounds__(1024) void k_scan2(
    int* __restrict__ offsets, const int* __restrict__ blksum, int nblk, int n)
{
    __shared__ int base_sh, tot_sh;
    const int tid = threadIdx.x, lane = tid & 63, wv = tid >> 6;
    if (wv == 0) {
        int v = (lane < nblk) ? blksum[lane] : 0;
        int x = v;
        #pragma unroll
        for (int d = 1; d < 64; d <<= 1) { int t = __shfl_up(x, d); if (lane >= d) x += t; }
        int incl = __shfl(x, blockIdx.x);
        int own  = __shfl(v, blockIdx.x);
        int tot  = __shfl(x, nblk - 1);
        if (lane == 0) { base_sh = incl - own; tot_sh = tot; }
    }
    __syncthreads();
    const int i = blockIdx.x * 1024 + tid;
    if (i < n) offsets[i] += base_sh;
    if (blockIdx.x == nblk - 1 && tid == 0) offsets[n] = tot_sh;
}

// ---------------- CSR build: bucket src indices by dst ----------------
__global__ __launch_bounds__(256) void k_bucket(
    const int* __restrict__ ei, const int* __restrict__ offsets,
    int* __restrict__ cursor, int* __restrict__ ss, int E)
{
    int e = blockIdx.x * 256 + threadIdx.x;
    if (e < E) {
        int d = ei[E + e];
        int pos = offsets[d] + atomicAdd(&cursor[d], 1);
        ss[pos] = ei[e];
    }
}

// ---------------- K2: gather-aggregate over interleaved bf16 rows -------------
__global__ __launch_bounds__(256) void k_agg(
    const unsigned short* __restrict__ xb, const int* __restrict__ offsets,
    const int* __restrict__ ss, unsigned short* __restrict__ aggb, int nn)
{
    const int tid = threadIdx.x;
    const int lane = tid & 63;
    const int wv = tid >> 6;
    const int d = blockIdx.x * 4 + wv;
    if (d >= nn) return;
    const unsigned short* sp = xb + lane * 4;
    const int s0 = offsets[d], s1 = offsets[d + 1];
    float4 a = make_float4(0.f, 0.f, 0.f, 0.f);
    float4 a2 = make_float4(0.f, 0.f, 0.f, 0.f);
    int i = s0;
    for (; i + 4 <= s1; i += 4) {
        const int sA = ss[i], sB = ss[i + 1], sC = ss[i + 2], sD = ss[i + 3];
        const uint2 rA = *(const uint2*)(sp + (size_t)sA * 256);
        const uint2 rB = *(const uint2*)(sp + (size_t)sB * 256);
        const uint2 rC = *(const uint2*)(sp + (size_t)sC * 256);
        const uint2 rD = *(const uint2*)(sp + (size_t)sD * 256);
        a.x  += bf2f_lo(rA.x); a.y  += bf2f_hi(rA.x); a.z  += bf2f_lo(rA.y); a.w  += bf2f_hi(rA.y);
        a2.x += bf2f_lo(rB.x); a2.y += bf2f_hi(rB.x); a2.z += bf2f_lo(rB.y); a2.w += bf2f_hi(rB.y);
        a.x  += bf2f_lo(rC.x); a.y  += bf2f_hi(rC.x); a.z  += bf2f_lo(rC.y); a.w  += bf2f_hi(rC.y);
        a2.x += bf2f_lo(rD.x); a2.y += bf2f_hi(rD.x); a2.z += bf2f_lo(rD.y); a2.w += bf2f_hi(rD.y);
    }
    for (; i < s1; ++i) {
        const uint2 r = *(const uint2*)(sp + (size_t)ss[i] * 256);
        a.x += bf2f_lo(r.x); a.y += bf2f_hi(r.x); a.z += bf2f_lo(r.y); a.w += bf2f_hi(r.y);
    }
    a.x += a2.x; a.y += a2.y; a.z += a2.z; a.w += a2.w;
    ushort4 o;
    o.x = f2bf(a.x); o.y = f2bf(a.y); o.z = f2bf(a.z); o.w = f2bf(a.w);
    *(ushort4*)(aggb + (size_t)d * 256 + lane * 4) = o;
}

// ---------------- K3: (agg @ W) + gelu + MLP(128->64->32) + column sums -------
// 64 storage rows/block, 512 threads (8 waves). All matmuls on matrix cores.
// W-GEMM B-fragments read straight from global wtb (35 KB, L1/L2-hot across
// all 1563 blocks) so LDS stays ~50 KB -> 3 blocks/CU, 24 waves/CU.
// upool overlays: xa (agg tile) -> hsb (gelu out) -> h2p (layer2 out).
__global__ __launch_bounds__(512, 6) void k_mlp(
    const unsigned short* __restrict__ aggb, const unsigned short* __restrict__ wtb,
    const float* __restrict__ b0v,
    const unsigned short* __restrict__ w1tb, const float* __restrict__ b1v,
    const unsigned short* __restrict__ w2tb, const float* __restrict__ b2v,
    float* __restrict__ partials, int srows)
{
    __shared__ __align__(16) unsigned short wt1[64 * 136];      // 17.4 KB
    __shared__ __align__(16) unsigned short wt2[32 * 72];       // 4.6 KB
    __shared__ __align__(16) unsigned char upool[64 * 136 * 2]; // 17.4 KB: xa/hsb/h2p
    __shared__ __align__(16) unsigned short h1b[64 * 72];       // 9.2 KB
    __shared__ float b0s[DD], b1s[L1], b2s[L2];
    __shared__ float oacc[64];
    unsigned short* xa  = (unsigned short*)upool;   // [64][136] bf16 agg tile
    unsigned short* hsb = (unsigned short*)upool;   // [64][136] bf16 (after xa dead)
    float* h2p = (float*)upool;                     // [64][36] f32 (after hsb dead)

    const int tid = threadIdx.x;
    const int row0 = blockIdx.x * 64;

    for (int u = tid * 4; u < 64 * 136; u += 2048)
        *(uint2*)(&wt1[u]) = *(const uint2*)(w1tb + u);
    for (int u = tid * 4; u < 32 * 72; u += 2048)
        *(uint2*)(&wt2[u]) = *(const uint2*)(w2tb + u);
    if (tid < DD) b0s[tid] = b0v[tid];
    if (tid < L1) b1s[tid] = b1v[tid];
    if (tid < L2) b2s[tid] = b2v[tid];
    if (tid < 64) oacc[tid] = 0.f;

    // stage agg tile (raw bf16) -> xa
    for (int u = tid * 8; u < 64 * DD; u += 4096) {
        const int r = u >> 7, c = u & 127;
        uint4 raw = make_uint4(0, 0, 0, 0);
        if (row0 + r < srows) raw = *(const uint4*)(aggb + (size_t)(row0 + r) * HH + c);
        *(uint4*)(&xa[r * 136 + c]) = raw;
    }
    __syncthreads();

    const int lane = tid & 63;
    const int w = tid >> 6;       // 0..7
    const int lm = lane & 15;
    const int q = lane >> 4;
    const int r1 = (w & 3) * 16;  // row-tile base

    // W-GEMM (64x128 @ 128x128): wave w -> rows r1..+16, cols (w>>2)*64..+64
    {
        const int c0 = (w >> 2) * 64;
        const unsigned short* wcol = wtb + (size_t)(c0 + lm) * 136;
        v4f acc[4];
        #pragma unroll
        for (int i = 0; i < 4; ++i) acc[i] = (v4f)(0.f);
        #pragma unroll
        for (int ks = 0; ks < 4; ++ks) {
            const int k0 = ks * 32 + q * 8;
            const v8s af = *(const v8s*)(&xa[(r1 + lm) * 136 + k0]);
            #pragma unroll
            for (int ct = 0; ct < 4; ++ct) {
                const v8s bf = *(const v8s*)(wcol + ct * 16 * 136 + k0);
                acc[ct] = __builtin_amdgcn_mfma_f32_16x16x32_bf16(af, bf, acc[ct], 0, 0, 0);
            }
        }
        __syncthreads();   // all xa reads done; upool becomes hsb

        // bias + gelu on accumulators -> hsb (A-operand layout for layer1)
        #pragma unroll
        for (int ct = 0; ct < 4; ++ct) {
            const int col = c0 + ct * 16 + lm;
            const float bias = b0s[col];
            #pragma unroll
            for (int r = 0; r < 4; ++r)
                hsb[(r1 + q * 4 + r) * 136 + col] = f2bf(gelu_f(acc[ct][r] + bias));
        }
    }
    __syncthreads();

    // layer1 (64x128 @ 128x64): wave w -> rows r1..+16, cols (w>>2)*32..+32
    {
        const int c1 = (w >> 2) * 32;
        v4f a1[2];
        a1[0] = (v4f)(0.f); a1[1] = (v4f)(0.f);
        #pragma unroll
        for (int ks = 0; ks < 4; ++ks) {
            const int k0 = ks * 32 + q * 8;
            const v8s af = *(const v8s*)(&hsb[(r1 + lm) * 136 + k0]);
            #pragma unroll
            for (int ct = 0; ct < 2; ++ct) {
                const v8s bf = *(const v8s*)(&wt1[(c1 + ct * 16 + lm) * 136 + k0]);
                a1[ct] = __builtin_amdgcn_mfma_f32_16x16x32_bf16(af, bf, a1[ct], 0, 0, 0);
            }
        }
        #pragma unroll
        for (int ct = 0; ct < 2; ++ct) {
            const int col = c1 + ct * 16 + lm;
            const float bias = b1s[col];
            #pragma unroll
            for (int r = 0; r < 4; ++r)
                h1b[(r1 + q * 4 + r) * 72 + col] = f2bf(fmaxf(a1[ct][r] + bias, 0.f));
        }
    }
    __syncthreads();

    // layer2 (64x64 @ 64x32): wave w -> rows r1..+16, cols (w>>2)*16..+16
    {
        const int c2 = (w >> 2) * 16;
        v4f a2 = (v4f)(0.f);
        #pragma unroll
        for (int ks = 0; ks < 2; ++ks) {
            const int k0 = ks * 32 + q * 8;
            const v8s af = *(const v8s*)(&h1b[(r1 + lm) * 72 + k0]);
            const v8s bf = *(const v8s*)(&wt2[(c2 + lm) * 72 + k0]);
            a2 = __builtin_amdgcn_mfma_f32_16x16x32_bf16(af, bf, a2, 0, 0, 0);
        }
        __syncthreads();   // h1b reads done; upool (hsb) becomes h2p
        const int col = c2 + lm;
        const float bias = b2s[col];
        #pragma unroll
        for (int r = 0; r < 4; ++r)
            h2p[(r1 + q * 4 + r) * 36 + col] = fmaxf(a2[r] + bias, 0.f);
    }
    __syncthreads();

    // column sums: storage row r -> batch r&1
    {
        const int c = tid & 31;
        const int g = tid >> 5;   // 0..15, 4 rows each
        float p0 = 0.f, p1 = 0.f;
        #pragma unroll
        for (int i = 0; i < 4; ++i) {
            const int r = g * 4 + i;
            if (row0 + r < srows) {
                const float v = h2p[r * 36 + c];
                if (r & 1) p1 += v; else p0 += v;
            }
        }
        if (p0 != 0.f) atomicAdd(&oacc[c], p0);
        if (p1 != 0.f) atomicAdd(&oacc[32 + c], p1);
    }
    __syncthreads();
    if (tid < 64) partials[(size_t)blockIdx.x * 64 + tid] = oacc[tid];
}

// ---------------- Fallback path (ws too small for CSR) ----------------
__global__ __launch_bounds__(256) void k_scatter(
    const int* __restrict__ ei, const unsigned short* __restrict__ xb,
    float* __restrict__ aggf, int E)
{
    const int tid = threadIdx.x;
    const int eg = tid >> 6;
    const int lane = tid & 63;
    const int e = blockIdx.x * 4 + eg;
    if (e >= E) return;
    const int src = ei[e];
    const int dst = ei[E + e];
    const uint2 r = *(const uint2*)(xb + (size_t)src * 256 + lane * 4);
    float* ap = aggf + (size_t)dst * 256 + lane * 4;
    unsafeAtomicAdd(ap + 0, bf2f_lo(r.x));
    unsafeAtomicAdd(ap + 1, bf2f_hi(r.x));
    unsafeAtomicAdd(ap + 2, bf2f_lo(r.y));
    unsafeAtomicAdd(ap + 3, bf2f_hi(r.y));
}

__global__ __launch_bounds__(256) void k_cvt(
    const float* __restrict__ in, unsigned short* __restrict__ outb, int n)
{
    int i = blockIdx.x * 256 + threadIdx.x;
    if (i < n) outb[i] = f2bf(in[i]);
}

// ---------------- K4a: parallel reduce of partials ----------------
__global__ __launch_bounds__(256) void k_reduce(
    const float* __restrict__ partials, float* __restrict__ accum, int nblk)
{
    __shared__ float lsum[4][64];
    const int t = threadIdx.x & 63;
    const int w = threadIdx.x >> 6;
    float s = 0.f;
    for (int g = blockIdx.x * 4 + w; g < nblk; g += gridDim.x * 4)
        s += partials[(size_t)g * 64 + t];
    lsum[w][t] = s;
    __syncthreads();
    if (threadIdx.x < 64) {
        const float v = lsum[0][t] + lsum[1][t] + lsum[2][t] + lsum[3][t];
        unsafeAtomicAdd(&accum[t], v);
    }
}

// ---------------- K4b: apply layer3 to mean(h2) ----------------
__global__ __launch_bounds__(64) void k_final(
    const float* __restrict__ accum, const float* __restrict__ W3,
    const float* __restrict__ b3v, float* __restrict__ out)
{
    const int tid = threadIdx.x;
    if (tid < 2 * OO) {
        const int b = tid / OO, o = tid % OO;
        float acc = b3v[o];
        const float inv = 1.0f / (float)NN;
        #pragma unroll
        for (int j = 0; j < L2; ++j) acc += (accum[b * 32 + j] * inv) * W3[j * OO + o];
        out[tid] = acc;
    }
}

extern "C" void kernel_launch(void* const* d_in, const int* in_sizes, int n_in,
                              void* d_out, int out_size, void* d_ws, size_t ws_size,
                              hipStream_t stream) {
    const float* x  = (const float*)d_in[0];
    const int*   ei = (const int*)d_in[1];
    const float* W  = (const float*)d_in[2];
    const float* b0 = (const float*)d_in[3];
    const float* W1 = (const float*)d_in[4];
    const float* b1 = (const float*)d_in[5];
    const float* W2 = (const float*)d_in[6];
    const float* b2 = (const float*)d_in[7];
    const float* W3 = (const float*)d_in[8];
    const float* b3 = (const float*)d_in[9];
    float* out = (float*)d_out;

    const int E = in_sizes[1] / 2;           // 800000
    const int rows = 2 * NN;                 // 100000 storage rows
    const int nblk = (rows + 63) / 64;       // 1563 (mlp blocks)
    const int nsb = (NN + 1023) / 1024;      // 49 scan blocks
    const int wpn = 128 * 136 + 64 * 136 + 32 * 72;   // 28416 prep elements

    // workspace layout
    unsigned short* xb   = (unsigned short*)d_ws;                    // rows*HH bf16 (interleaved x)
    unsigned short* aggb = xb + (size_t)rows * HH;                   // rows*HH bf16 (interleaved)
    float* partials = (float*)(aggb + (size_t)rows * HH);            // nblk*64
    float* accum    = partials + (size_t)nblk * 64;                  // 64
    int*   counts   = (int*)(accum + 64);                            // NN
    int*   cursor   = counts + NN;                                   // NN
    int*   offsets  = cursor + NN;                                   // NN+1
    int*   blksum   = offsets + NN + 1;                              // 64
    unsigned short* wtb  = (unsigned short*)(blksum + 64);           // 128*136
    unsigned short* w1tb = wtb + 128 * 136;                          // 64*136
    unsigned short* w2tb = w1tb + 64 * 136;                          // 32*72
    int*   ss       = (int*)(w2tb + 32 * 72);                        // E
    float* aggf     = (float*)(ss + E);                              // rows*HH (fallback only)
    const size_t need_csr = ((size_t)rows * HH * 2 + wpn) * sizeof(unsigned short)
                      + ((size_t)nblk * 64 + 64) * sizeof(float)
                      + ((size_t)NN * 3 + 1 + 64 + E) * sizeof(int);
    const size_t need_fb = need_csr + (size_t)rows * HH * sizeof(float);

    if (ws_size >= need_csr && nsb <= 64) {
        hipMemsetAsync(accum, 0, (64 + 2 * (size_t)NN) * sizeof(int), stream);
        k_wprep<<<dim3((wpn + 255) / 256), dim3(256), 0, stream>>>(W, W1, W2, wtb, w1tb, w2tb);
        k_xcvt<<<dim3(2048), dim3(256), 0, stream>>>(x, xb, ei, counts, E);
        k_scan1<<<dim3(nsb), dim3(1024), 0, stream>>>(counts, offsets, blksum, NN);
        k_scan2<<<dim3(nsb), dim3(1024), 0, stream>>>(offsets, blksum, nsb, NN);
        k_bucket<<<dim3((E + 255) / 256), dim3(256), 0, stream>>>(ei, offsets, cursor, ss, E);
        k_agg<<<dim3((NN + 3) / 4), dim3(256), 0, stream>>>(xb, offsets, ss, aggb, NN);
        k_mlp<<<dim3(nblk), dim3(512), 0, stream>>>(aggb, wtb, b0, w1tb, b1, w2tb, b2, partials, rows);
    } else if (ws_size >= need_fb) {
        hipMemsetAsync(accum, 0, 64 * sizeof(float), stream);
        hipMemsetAsync(aggf, 0, (size_t)rows * HH * sizeof(float), stream);
        k_wprep<<<dim3((wpn + 255) / 256), dim3(256), 0, stream>>>(W, W1, W2, wtb, w1tb, w2tb);
        k_xcvt<<<dim3(2048), dim3(256), 0, stream>>>(x, xb, ei, counts, 0);
        k_scatter<<<dim3((E + 3) / 4), dim3(256), 0, stream>>>(ei, xb, aggf, E);
        k_cvt<<<dim3((rows * HH + 255) / 256), dim3(256), 0, stream>>>(aggf, aggb, rows * HH);
        k_mlp<<<dim3(nblk), dim3(512), 0, stream>>>(aggb, wtb, b0, w1tb, b1, w2tb, b2, partials, rows);
    }

    k_reduce<<<dim3(64), dim3(256), 0, stream>>>(partials, accum, nblk);
    k_final<<<dim3(1), dim3(64), 0, stream>>>(accum, W3, b3, out);
}

// Round 2
// 264.756 us; speedup vs baseline: 1.0645x; 1.0645x over previous
//
#include <hip/hip_runtime.h>
#include <math.h>

#define NN 50000
#define DD 128
#define HH 128
#define L1 64
#define L2 32
#define OO 10

// packed B-fragment table sizes (ct * ks * 64 lanes * 8 elems)
#define NW0 16384   // W : 8 ct * 4 ks * 64 * 8
#define NW1 8192    // W1: 4 ct * 4 ks * 64 * 8
#define NW2 2048    // W2: 2 ct * 2 ks * 64 * 8

typedef short v8s __attribute__((ext_vector_type(8)));   // 8 bf16 (4 VGPRs)
typedef float v4f __attribute__((ext_vector_type(4)));   // MFMA accumulator

// ---- bf16 helpers (manual: RNE pack) ----
__device__ __forceinline__ float bf2f_lo(unsigned u) { return __uint_as_float(u << 16); }
__device__ __forceinline__ float bf2f_hi(unsigned u) { return __uint_as_float(u & 0xffff0000u); }
__device__ __forceinline__ unsigned short f2bf(float f) {
    unsigned u = __float_as_uint(f);
    return (unsigned short)((u + 0x7fffu + ((u >> 16) & 1u)) >> 16);
}
__device__ __forceinline__ unsigned pack2(float lo, float hi) {
    return (unsigned)f2bf(lo) | ((unsigned)f2bf(hi) << 16);
}
__device__ __forceinline__ float gelu_f(float v) {
    return 0.5f * v * (1.f + erff(v * 0.70710678118654752f));
}

// ---------------- K0: pack W, W1, W2 into MFMA B-fragment order ----------------
// frag index: ((ct*KS + ks)*64 + lane)*8 + e ; element = Wx[k][n],
// k = ks*32 + (lane>>4)*8 + e, n = ct*16 + (lane&15).
// A wave's B-load is then 64 lanes x 16B contiguous (1KB coalesced burst).
__global__ __launch_bounds__(256) void k_wprep(
    const float* __restrict__ W, const float* __restrict__ W1,
    const float* __restrict__ W2, unsigned short* __restrict__ wtp,
    unsigned short* __restrict__ w1tp, unsigned short* __restrict__ w2tp)
{
    int i = blockIdx.x * 256 + threadIdx.x;
    if (i < NW0) {
        const int e = i & 7, ln = (i >> 3) & 63, ks = (i >> 9) & 3, ct = i >> 11;
        wtp[i] = f2bf(W[(ks * 32 + (ln >> 4) * 8 + e) * HH + ct * 16 + (ln & 15)]);
    } else if (i < NW0 + NW1) {
        const int j = i - NW0;
        const int e = j & 7, ln = (j >> 3) & 63, ks = (j >> 9) & 3, ct = j >> 11;
        w1tp[j] = f2bf(W1[(ks * 32 + (ln >> 4) * 8 + e) * L1 + ct * 16 + (ln & 15)]);
    } else if (i < NW0 + NW1 + NW2) {
        const int j = i - NW0 - NW1;
        const int e = j & 7, ln = (j >> 3) & 63, ks = (j >> 9) & 1, ct = j >> 10;
        w2tp[j] = f2bf(W2[(ks * 32 + (ln >> 4) * 8 + e) * L2 + ct * 16 + (ln & 15)]);
    }
}

// ---------------- K1: x -> interleaved bf16 + fused dst histogram -------------
__global__ __launch_bounds__(256) void k_xcvt(
    const float* __restrict__ x, unsigned short* __restrict__ xb,
    const int* __restrict__ ei, int* __restrict__ counts, int E)
{
    const int gid = blockIdx.x * 256 + threadIdx.x;
    const int stride = gridDim.x * 256;
    const int HALF = NN * 32;                 // float4-chunks per batch
    for (int idx = gid; idx < 2 * HALF; idx += stride) {
        const int b = (idx >= HALF) ? 1 : 0;
        const int j = idx - b * HALF;
        const int n = j >> 5;
        const int c4 = j & 31;
        const float4 v = *(const float4*)(x + ((size_t)b * NN + n) * DD + c4 * 4);
        ushort4 o;
        o.x = f2bf(v.x); o.y = f2bf(v.y); o.z = f2bf(v.z); o.w = f2bf(v.w);
        *(ushort4*)(xb + ((size_t)n * 2 + b) * DD + c4 * 4) = o;
    }
    for (int e = gid; e < E; e += stride)
        atomicAdd(&counts[ei[(size_t)E + e]], 1);
}

// ---------------- multi-block scan, stage 1 ----------------
__global__ __launch_bounds__(1024) void k_scan1(
    const int* __restrict__ counts, int* __restrict__ offsets,
    int* __restrict__ blksum, int n)
{
    __shared__ int wsum[16], woff[16];
    const int tid = threadIdx.x, lane = tid & 63, wv = tid >> 6;
    const int i = blockIdx.x * 1024 + tid;
    int v = (i < n) ? counts[i] : 0;
    int x = v;
    #pragma unroll
    for (int d = 1; d < 64; d <<= 1) { int t = __shfl_up(x, d); if (lane >= d) x += t; }
    if (lane == 63) wsum[wv] = x;
    __syncthreads();
    if (wv == 0 && lane < 16) {
        int y = wsum[lane];
        #pragma unroll
        for (int d = 1; d < 16; d <<= 1) { int t = __shfl_up(y, d); if (lane >= d) y += t; }
        woff[lane] = y - wsum[lane];
        if (lane == 15) blksum[blockIdx.x] = y;
    }
    __syncthreads();
    if (i < n) offsets[i] = woff[wv] + (x - v);
}

// ---------------- multi-block scan, stage 2 ----------------
__global__ __launch_bounds__(1024) void k_scan2(
    int* __restrict__ offsets, const int* __restrict__ blksum, int nblk, int n)
{
    __shared__ int base_sh, tot_sh;
    const int tid = threadIdx.x, lane = tid & 63, wv = tid >> 6;
    if (wv == 0) {
        int v = (lane < nblk) ? blksum[lane] : 0;
        int x = v;
        #pragma unroll
        for (int d = 1; d < 64; d <<= 1) { int t = __shfl_up(x, d); if (lane >= d) x += t; }
        int incl = __shfl(x, blockIdx.x);
        int own  = __shfl(v, blockIdx.x);
        int tot  = __shfl(x, nblk - 1);
        if (lane == 0) { base_sh = incl - own; tot_sh = tot; }
    }
    __syncthreads();
    const int i = blockIdx.x * 1024 + tid;
    if (i < n) offsets[i] += base_sh;
    if (blockIdx.x == nblk - 1 && tid == 0) offsets[n] = tot_sh;
}

// ---------------- CSR build: bucket src indices by dst ----------------
__global__ __launch_bounds__(256) void k_bucket(
    const int* __restrict__ ei, const int* __restrict__ offsets,
    int* __restrict__ cursor, int* __restrict__ ss, int E)
{
    int e = blockIdx.x * 256 + threadIdx.x;
    if (e < E) {
        int d = ei[E + e];
        int pos = offsets[d] + atomicAdd(&cursor[d], 1);
        ss[pos] = ei[e];
    }
}

// ---------------- K3: fused gather-agg + (agg @ W) + gelu + MLP + colsums ----
// Block: 32 nodes (64 storage rows), 512 threads (8 waves).
// FUSED: wave w aggregates nodes w*4..w*4+3 via CSR directly into LDS xa
//   (uint4 16B/lane: lanes 0-31 = even edges, 32-63 = odd edges, shfl_xor(32)
//    combine). Kills the aggb round-trip (51 MB) and the k_agg dispatch.
// All weight B-fragments come from packed global tables (coalesced 1KB bursts,
// L1-resident) -> no wt LDS staging; LDS ~28 KB.
template<bool FUSED>
__global__ __launch_bounds__(512, 6) void k_mlp_t(
    const unsigned short* __restrict__ src,   // FUSED ? xb : aggb
    const int* __restrict__ offsets, const int* __restrict__ ss,
    const unsigned short* __restrict__ wtp, const float* __restrict__ b0v,
    const unsigned short* __restrict__ w1tp, const float* __restrict__ b1v,
    const unsigned short* __restrict__ w2tp, const float* __restrict__ b2v,
    float* __restrict__ partials, int srows)
{
    __shared__ __align__(16) unsigned char upool[64 * 136 * 2]; // xa/hsb/h2p
    __shared__ __align__(16) unsigned short h1b[64 * 72];       // 9.2 KB
    __shared__ float b0s[DD], b1s[L1], b2s[L2];
    __shared__ float oacc[64];
    unsigned short* xa  = (unsigned short*)upool;   // [64][136] bf16 agg tile
    unsigned short* hsb = (unsigned short*)upool;   // [64][136] bf16 (after xa dead)
    float* h2p = (float*)upool;                     // [64][36] f32 (after hsb dead)

    const int tid = threadIdx.x;
    const int row0 = blockIdx.x * 64;
    const int lane = tid & 63;
    const int w = tid >> 6;       // 0..7

    if (tid < DD) b0s[tid] = b0v[tid];
    if (tid < L1) b1s[tid] = b1v[tid];
    if (tid < L2) b2s[tid] = b2v[tid];
    if (tid < 64) oacc[tid] = 0.f;

    if (FUSED) {
        // gather-aggregate: wave w handles 4 nodes
        const int sel = (lane < 32) ? 0 : 1;
        const int co = (lane & 31) * 8;            // shorts offset in 512B row
        #pragma unroll
        for (int j = 0; j < 4; ++j) {
            const int ln = w * 4 + j;              // block-local node 0..31
            const int d = blockIdx.x * 32 + ln;    // global node
            const int s0 = (d < NN) ? offsets[d] : 0;
            const int s1 = (d < NN) ? offsets[d + 1] : 0;
            float a[8];
            #pragma unroll
            for (int t = 0; t < 8; ++t) a[t] = 0.f;
            int i = s0;
            for (; i + 4 <= s1; i += 4) {
                const int sA = ss[i + sel];
                const int sB = ss[i + 2 + sel];
                const uint4 ra = *(const uint4*)(src + (size_t)sA * 256 + co);
                const uint4 rb = *(const uint4*)(src + (size_t)sB * 256 + co);
                a[0] += bf2f_lo(ra.x); a[1] += bf2f_hi(ra.x);
                a[2] += bf2f_lo(ra.y); a[3] += bf2f_hi(ra.y);
                a[4] += bf2f_lo(ra.z); a[5] += bf2f_hi(ra.z);
                a[6] += bf2f_lo(ra.w); a[7] += bf2f_hi(ra.w);
                a[0] += bf2f_lo(rb.x); a[1] += bf2f_hi(rb.x);
                a[2] += bf2f_lo(rb.y); a[3] += bf2f_hi(rb.y);
                a[4] += bf2f_lo(rb.z); a[5] += bf2f_hi(rb.z);
                a[6] += bf2f_lo(rb.w); a[7] += bf2f_hi(rb.w);
            }
            if (i + 2 <= s1) {
                const int sA = ss[i + sel];
                const uint4 ra = *(const uint4*)(src + (size_t)sA * 256 + co);
                a[0] += bf2f_lo(ra.x); a[1] += bf2f_hi(ra.x);
                a[2] += bf2f_lo(ra.y); a[3] += bf2f_hi(ra.y);
                a[4] += bf2f_lo(ra.z); a[5] += bf2f_hi(ra.z);
                a[6] += bf2f_lo(ra.w); a[7] += bf2f_hi(ra.w);
                i += 2;
            }
            if (i < s1 && lane < 32) {
                const int sA = ss[i];
                const uint4 ra = *(const uint4*)(src + (size_t)sA * 256 + co);
                a[0] += bf2f_lo(ra.x); a[1] += bf2f_hi(ra.x);
                a[2] += bf2f_lo(ra.y); a[3] += bf2f_hi(ra.y);
                a[4] += bf2f_lo(ra.z); a[5] += bf2f_hi(ra.z);
                a[6] += bf2f_lo(ra.w); a[7] += bf2f_hi(ra.w);
            }
            #pragma unroll
            for (int t = 0; t < 8; ++t) a[t] += __shfl_xor(a[t], 32);
            if (lane < 32) {
                const int tr = ln * 2 + (lane >> 4);   // storage row in tile
                const int col = (lane & 15) * 8;
                uint4 o;
                o.x = pack2(a[0], a[1]); o.y = pack2(a[2], a[3]);
                o.z = pack2(a[4], a[5]); o.w = pack2(a[6], a[7]);
                *(uint4*)(&xa[tr * 136 + col]) = o;
            }
        }
    } else {
        // stage pre-aggregated tile (fallback path)
        for (int u = tid * 8; u < 64 * DD; u += 4096) {
            const int r = u >> 7, c = u & 127;
            uint4 raw = make_uint4(0, 0, 0, 0);
            if (row0 + r < srows) raw = *(const uint4*)(src + (size_t)(row0 + r) * HH + c);
            *(uint4*)(&xa[r * 136 + c]) = raw;
        }
    }
    __syncthreads();

    const int lm = lane & 15;
    const int q = lane >> 4;
    const int r1 = (w & 3) * 16;  // row-tile base
    const int ch = w >> 2;        // column half 0/1

    // W-GEMM (64x128 @ 128x128): wave w -> rows r1..+16, cols ch*64..+64
    {
        v4f acc[4];
        #pragma unroll
        for (int i = 0; i < 4; ++i) acc[i] = (v4f)(0.f);
        #pragma unroll
        for (int ks = 0; ks < 4; ++ks) {
            const int k0 = ks * 32 + q * 8;
            const v8s af = *(const v8s*)(&xa[(r1 + lm) * 136 + k0]);
            #pragma unroll
            for (int ct = 0; ct < 4; ++ct) {
                const int ctg = ch * 4 + ct;
                const v8s bf = *(const v8s*)(wtp + ((size_t)(ctg * 4 + ks) * 64 + lane) * 8);
                acc[ct] = __builtin_amdgcn_mfma_f32_16x16x32_bf16(af, bf, acc[ct], 0, 0, 0);
            }
        }
        __syncthreads();   // all xa reads done; upool becomes hsb

        // bias + gelu -> hsb (A-operand layout for layer1)
        #pragma unroll
        for (int ct = 0; ct < 4; ++ct) {
            const int col = ch * 64 + ct * 16 + lm;
            const float bias = b0s[col];
            #pragma unroll
            for (int r = 0; r < 4; ++r)
                hsb[(r1 + q * 4 + r) * 136 + col] = f2bf(gelu_f(acc[ct][r] + bias));
        }
    }
    __syncthreads();

    // layer1 (64x128 @ 128x64): wave w -> rows r1..+16, cols ch*32..+32
    {
        v4f a1[2];
        a1[0] = (v4f)(0.f); a1[1] = (v4f)(0.f);
        #pragma unroll
        for (int ks = 0; ks < 4; ++ks) {
            const int k0 = ks * 32 + q * 8;
            const v8s af = *(const v8s*)(&hsb[(r1 + lm) * 136 + k0]);
            #pragma unroll
            for (int ct = 0; ct < 2; ++ct) {
                const int ctg = ch * 2 + ct;
                const v8s bf = *(const v8s*)(w1tp + ((size_t)(ctg * 4 + ks) * 64 + lane) * 8);
                a1[ct] = __builtin_amdgcn_mfma_f32_16x16x32_bf16(af, bf, a1[ct], 0, 0, 0);
            }
        }
        #pragma unroll
        for (int ct = 0; ct < 2; ++ct) {
            const int col = ch * 32 + ct * 16 + lm;
            const float bias = b1s[col];
            #pragma unroll
            for (int r = 0; r < 4; ++r)
                h1b[(r1 + q * 4 + r) * 72 + col] = f2bf(fmaxf(a1[ct][r] + bias, 0.f));
        }
    }
    __syncthreads();

    // layer2 (64x64 @ 64x32): wave w -> rows r1..+16, cols ch*16..+16
    {
        v4f a2 = (v4f)(0.f);
        #pragma unroll
        for (int ks = 0; ks < 2; ++ks) {
            const int k0 = ks * 32 + q * 8;
            const v8s af = *(const v8s*)(&h1b[(r1 + lm) * 72 + k0]);
            const v8s bf = *(const v8s*)(w2tp + ((size_t)(ch * 2 + ks) * 64 + lane) * 8);
            a2 = __builtin_amdgcn_mfma_f32_16x16x32_bf16(af, bf, a2, 0, 0, 0);
        }
        __syncthreads();   // hsb (upool) reads long done; reuse as h2p
        const int col = ch * 16 + lm;
        const float bias = b2s[col];
        #pragma unroll
        for (int r = 0; r < 4; ++r)
            h2p[(r1 + q * 4 + r) * 36 + col] = fmaxf(a2[r] + bias, 0.f);
    }
    __syncthreads();

    // column sums: storage row r -> batch r&1
    {
        const int c = tid & 31;
        const int g = tid >> 5;   // 0..15, 4 rows each
        float p0 = 0.f, p1 = 0.f;
        #pragma unroll
        for (int i = 0; i < 4; ++i) {
            const int r = g * 4 + i;
            if (row0 + r < srows) {
                const float v = h2p[r * 36 + c];
                if (r & 1) p1 += v; else p0 += v;
            }
        }
        if (p0 != 0.f) atomicAdd(&oacc[c], p0);
        if (p1 != 0.f) atomicAdd(&oacc[32 + c], p1);
    }
    __syncthreads();
    if (tid < 64) partials[(size_t)blockIdx.x * 64 + tid] = oacc[tid];
}

// ---------------- Fallback path (ws too small for CSR) ----------------
__global__ __launch_bounds__(256) void k_scatter(
    const int* __restrict__ ei, const unsigned short* __restrict__ xb,
    float* __restrict__ aggf, int E)
{
    const int tid = threadIdx.x;
    const int eg = tid >> 6;
    const int lane = tid & 63;
    const int e = blockIdx.x * 4 + eg;
    if (e >= E) return;
    const int src = ei[e];
    const int dst = ei[E + e];
    const uint2 r = *(const uint2*)(xb + (size_t)src * 256 + lane * 4);
    float* ap = aggf + (size_t)dst * 256 + lane * 4;
    unsafeAtomicAdd(ap + 0, bf2f_lo(r.x));
    unsafeAtomicAdd(ap + 1, bf2f_hi(r.x));
    unsafeAtomicAdd(ap + 2, bf2f_lo(r.y));
    unsafeAtomicAdd(ap + 3, bf2f_hi(r.y));
}

__global__ __launch_bounds__(256) void k_cvt(
    const float* __restrict__ in, unsigned short* __restrict__ outb, int n)
{
    int i = blockIdx.x * 256 + threadIdx.x;
    if (i < n) outb[i] = f2bf(in[i]);
}

// ---------------- K4a: parallel reduce of partials ----------------
__global__ __launch_bounds__(256) void k_reduce(
    const float* __restrict__ partials, float* __restrict__ accum, int nblk)
{
    __shared__ float lsum[4][64];
    const int t = threadIdx.x & 63;
    const int w = threadIdx.x >> 6;
    float s = 0.f;
    for (int g = blockIdx.x * 4 + w; g < nblk; g += gridDim.x * 4)
        s += partials[(size_t)g * 64 + t];
    lsum[w][t] = s;
    __syncthreads();
    if (threadIdx.x < 64) {
        const float v = lsum[0][t] + lsum[1][t] + lsum[2][t] + lsum[3][t];
        unsafeAtomicAdd(&accum[t], v);
    }
}

// ---------------- K4b: apply layer3 to mean(h2) ----------------
__global__ __launch_bounds__(64) void k_final(
    const float* __restrict__ accum, const float* __restrict__ W3,
    const float* __restrict__ b3v, float* __restrict__ out)
{
    const int tid = threadIdx.x;
    if (tid < 2 * OO) {
        const int b = tid / OO, o = tid % OO;
        float acc = b3v[o];
        const float inv = 1.0f / (float)NN;
        #pragma unroll
        for (int j = 0; j < L2; ++j) acc += (accum[b * 32 + j] * inv) * W3[j * OO + o];
        out[tid] = acc;
    }
}

extern "C" void kernel_launch(void* const* d_in, const int* in_sizes, int n_in,
                              void* d_out, int out_size, void* d_ws, size_t ws_size,
                              hipStream_t stream) {
    const float* x  = (const float*)d_in[0];
    const int*   ei = (const int*)d_in[1];
    const float* W  = (const float*)d_in[2];
    const float* b0 = (const float*)d_in[3];
    const float* W1 = (const float*)d_in[4];
    const float* b1 = (const float*)d_in[5];
    const float* W2 = (const float*)d_in[6];
    const float* b2 = (const float*)d_in[7];
    const float* W3 = (const float*)d_in[8];
    const float* b3 = (const float*)d_in[9];
    float* out = (float*)d_out;

    const int E = in_sizes[1] / 2;           // 800000
    const int rows = 2 * NN;                 // 100000 storage rows
    const int nblk = (rows + 63) / 64;       // 1563 (mlp blocks, 32 nodes each)
    const int nsb = (NN + 1023) / 1024;      // 49 scan blocks
    const int wpn = NW0 + NW1 + NW2;         // 26624 packed weight elements

    // workspace layout
    unsigned short* xb   = (unsigned short*)d_ws;                    // rows*HH bf16 (interleaved x)
    unsigned short* aggb = xb + (size_t)rows * HH;                   // rows*HH bf16 (fallback only)
    float* partials = (float*)(aggb + (size_t)rows * HH);            // nblk*64
    float* accum    = partials + (size_t)nblk * 64;                  // 64
    int*   counts   = (int*)(accum + 64);                            // NN
    int*   cursor   = counts + NN;                                   // NN
    int*   offsets  = cursor + NN;                                   // NN+1
    int*   blksum   = offsets + NN + 1;                              // 64
    unsigned short* wtp = (unsigned short*)(((uintptr_t)(blksum + 64) + 15) & ~(uintptr_t)15);
    unsigned short* w1tp = wtp + NW0;
    unsigned short* w2tp = w1tp + NW1;
    int*   ss       = (int*)(w2tp + NW2);                            // E
    float* aggf     = (float*)(ss + E);                              // rows*HH (fallback only)
    const size_t need_csr = ((size_t)rows * HH * 2 + wpn) * sizeof(unsigned short)
                      + ((size_t)nblk * 64 + 64) * sizeof(float)
                      + ((size_t)NN * 3 + 1 + 64 + E) * sizeof(int) + 16;
    const size_t need_fb = need_csr + (size_t)rows * HH * sizeof(float);

    if (ws_size >= need_csr && nsb <= 64) {
        hipMemsetAsync(accum, 0, (64 + 2 * (size_t)NN) * sizeof(int), stream);
        k_wprep<<<dim3((wpn + 255) / 256), dim3(256), 0, stream>>>(W, W1, W2, wtp, w1tp, w2tp);
        k_xcvt<<<dim3(2048), dim3(256), 0, stream>>>(x, xb, ei, counts, E);
        k_scan1<<<dim3(nsb), dim3(1024), 0, stream>>>(counts, offsets, blksum, NN);
        k_scan2<<<dim3(nsb), dim3(1024), 0, stream>>>(offsets, blksum, nsb, NN);
        k_bucket<<<dim3((E + 255) / 256), dim3(256), 0, stream>>>(ei, offsets, cursor, ss, E);
        k_mlp_t<true><<<dim3(nblk), dim3(512), 0, stream>>>(
            xb, offsets, ss, wtp, b0, w1tp, b1, w2tp, b2, partials, rows);
    } else if (ws_size >= need_fb) {
        hipMemsetAsync(accum, 0, 64 * sizeof(float), stream);
        hipMemsetAsync(aggf, 0, (size_t)rows * HH * sizeof(float), stream);
        k_wprep<<<dim3((wpn + 255) / 256), dim3(256), 0, stream>>>(W, W1, W2, wtp, w1tp, w2tp);
        k_xcvt<<<dim3(2048), dim3(256), 0, stream>>>(x, xb, ei, counts, 0);
        k_scatter<<<dim3((E + 3) / 4), dim3(256), 0, stream>>>(ei, xb, aggf, E);
        k_cvt<<<dim3((rows * HH + 255) / 256), dim3(256), 0, stream>>>(aggf, aggb, rows * HH);
        k_mlp_t<false><<<dim3(nblk), dim3(512), 0, stream>>>(
            aggb, offsets, ss, wtp, b0, w1tp, b1, w2tp, b2, partials, rows);
    }

    k_reduce<<<dim3(64), dim3(256), 0, stream>>>(partials, accum, nblk);
    k_final<<<dim3(1), dim3(64), 0, stream>>>(accum, W3, b3, out);
}